// Round 1
// baseline (170.530 us; speedup 1.0000x reference)
//
#include <hip/hip_runtime.h>
#include <math.h>

#define N 8
#define C 128
#define L 1024
#define K 100
#define TEMP 0.5f
#define EPS 1e-8f

// dst[n][l][ch] = src[(n*C+ch)*slen + off + l]   (tiled 32x32 transpose, per n)
__global__ void transpose_kernel(const float* __restrict__ src, float* __restrict__ dst,
                                 int slen, int off) {
    __shared__ float tile[32][33];          // +1 pad: conflict-free
    const int n  = blockIdx.z;
    const int l0 = blockIdx.x * 32;
    const int c0 = blockIdx.y * 32;
    const int tx = threadIdx.x, ty = threadIdx.y;   // block (32,8)
#pragma unroll
    for (int i = 0; i < 4; i++) {
        int ch = c0 + ty + i * 8;
        tile[ty + i * 8][tx] = src[((size_t)(n * C + ch)) * slen + off + l0 + tx];
    }
    __syncthreads();
#pragma unroll
    for (int i = 0; i < 4; i++) {
        int l = l0 + ty + i * 8;
        dst[((size_t)n * L + l) * C + c0 + tx] = tile[tx][ty + i * 8];
    }
}

// One 128-thread block per (n,t). s_c = context vector (LDS broadcast).
// Thread k computes logit for target k (k=0: positive=z row t; k>=1: negatives).
__global__ void __launch_bounds__(128)
ssl_main(const float* __restrict__ z_t, const float* __restrict__ c_t,
         const int* __restrict__ neg_inds, float* __restrict__ out) {
    const int t = blockIdx.x;
    const int n = blockIdx.y;
    const int tid = threadIdx.x;
    __shared__ float s_c[C];
    const size_t row_nt = (size_t)n * L + t;
    s_c[tid] = c_t[row_nt * C + tid];
    __syncthreads();
    if (tid >= K + 1) return;

    const int idx = (tid == 0) ? t : neg_inds[row_nt * K + (tid - 1)];
    const float4* rz = (const float4*)(z_t + ((size_t)n * L + idx) * C);
    const float4* rc = (const float4*)s_c;

    float dot = 0.f, tn = 0.f, cn = 0.f;
    bool eq = true;
#pragma unroll 8
    for (int j = 0; j < C / 4; j++) {
        float4 a = rc[j];
        float4 b = rz[j];
        dot += a.x * b.x + a.y * b.y + a.z * b.z + a.w * b.w;
        tn  += b.x * b.x + b.y * b.y + b.z * b.z + b.w * b.w;
        cn  += a.x * a.x + a.y * a.y + a.z * a.z + a.w * a.w;
        eq = eq && (a.x == b.x) && (a.y == b.y) && (a.z == b.z) && (a.w == b.w);
    }
    float denom = fmaxf(sqrtf(cn), EPS) * fmaxf(sqrtf(tn), EPS) * TEMP;
    float logit = dot / denom;
    if (tid > 0 && eq) logit = -INFINITY;   // neg identical to context vector
    out[row_nt * (K + 1) + tid] = logit;
}

extern "C" void kernel_launch(void* const* d_in, const int* in_sizes, int n_in,
                              void* d_out, int out_size, void* d_ws, size_t ws_size,
                              hipStream_t stream) {
    const float* z   = (const float*)d_in[0];   // (N, C, L)
    const float* c   = (const float*)d_in[1];   // (N, C, L+1)
    const int*   neg = (const int*)d_in[2];     // (N, L, K)
    float* out = (float*)d_out;                 // (N*L, K+1)

    float* z_t = (float*)d_ws;                  // (N, L, C)  4 MB
    float* c_t = z_t + (size_t)N * L * C;       // (N, L, C)  4 MB

    dim3 tb(32, 8);
    dim3 tg(L / 32, C / 32, N);
    transpose_kernel<<<tg, tb, 0, stream>>>(z, z_t, L, 0);
    transpose_kernel<<<tg, tb, 0, stream>>>(c, c_t, L + 1, 1);  // skip col 0

    ssl_main<<<dim3(L, N), 128, 0, stream>>>(z_t, c_t, neg, out);
}

// Round 2
// 101.930 us; speedup vs baseline: 1.6730x; 1.6730x over previous
//
#include <hip/hip_runtime.h>
#include <math.h>

#define N 8
#define C 128
#define L 1024
#define K 100
#define TEMP 0.5f
#define EPS 1e-8f

__device__ __forceinline__ float dp4(float4 a, float4 b) {
    return a.x * b.x + a.y * b.y + a.z * b.z + a.w * b.w;
}
__device__ __forceinline__ float ad4(float4 a, float4 b) {
    return fabsf(a.x - b.x) + fabsf(a.y - b.y) + fabsf(a.z - b.z) + fabsf(a.w - b.w);
}

// Fused transpose for z and c: dst[n][l][ch] = src[(n*C+ch)*slen + off + l]
// blockIdx.z in [0,16): 0-7 -> z slab n, 8-15 -> c slab n (skip col 0)
__global__ void __launch_bounds__(512)
transpose_both(const float* __restrict__ z, const float* __restrict__ c,
               float* __restrict__ z_t, float* __restrict__ c_t) {
    __shared__ float tile[64][65];
    const int which = blockIdx.z >> 3;
    const int n = blockIdx.z & 7;
    const float* src = which ? c : z;
    float* dst = which ? c_t : z_t;
    const int slen = which ? (L + 1) : L;
    const int off = which;
    const int l0 = blockIdx.x * 64;
    const int c0 = blockIdx.y * 64;
    const int tx = threadIdx.x;   // 0..63
    const int ty = threadIdx.y;   // 0..7
#pragma unroll
    for (int i = 0; i < 8; i++) {
        int ch = c0 + ty + i * 8;
        tile[ty + i * 8][tx] = src[((size_t)(n * C + ch)) * slen + off + l0 + tx];
    }
    __syncthreads();
#pragma unroll
    for (int i = 0; i < 8; i++) {
        int l = l0 + ty + i * 8;
        dst[((size_t)n * L + l) * C + c0 + tx] = tile[tx][ty + i * 8];
    }
}

// One wave per (n,t). 16 lanes per target, 4 targets per wave-iteration.
// Lane s of group g loads 32 B of the target row -> fully coalesced.
__global__ void __launch_bounds__(256)
ssl_main(const float* __restrict__ z_t, const float* __restrict__ c_t,
         const int* __restrict__ neg_inds, float* __restrict__ out) {
    const int tid  = threadIdx.x;
    const int lane = tid & 63;
    const int g    = lane >> 4;       // target group 0..3
    const int s    = lane & 15;       // 32B slice within row
    const int nt   = blockIdx.x * 4 + (tid >> 6);
    const int n    = nt >> 10;
    const int t    = nt & (L - 1);

    const float4* crow = (const float4*)(c_t + (size_t)nt * C);
    const float4 ca = crow[2 * s], cb = crow[2 * s + 1];
    float cn = dp4(ca, ca) + dp4(cb, cb);
#pragma unroll
    for (int o = 1; o < 16; o <<= 1) cn += __shfl_xor(cn, o);
    const float cdenom = fmaxf(sqrtf(cn), EPS) * TEMP;

    const int* ni = neg_inds + (size_t)nt * K;
    const float* zbase = z_t + (((size_t)n) << 10) * C;

    // Pipeline: z rows prefetched 1 iter ahead, indices 2 ahead.
    int k0   = g;
    int idx  = (k0 == 0) ? t : ni[k0 - 1];      // iter 0 (k=g<=3 always valid)
    int idx_n = ni[4 + g - 1];                  // iter 1 (k=4+g<=7 valid)
    const float4* zr = (const float4*)(zbase + (size_t)idx * C);
    float4 za = zr[2 * s], zb = zr[2 * s + 1];
    int idx_n2 = 0;

    for (int i = 0; i < 26; i++) {
        float4 zan = za, zbn = zb;
        if (i < 25) {                            // prefetch z row for iter i+1
            const float4* zrn = (const float4*)(zbase + (size_t)idx_n * C);
            zan = zrn[2 * s];
            zbn = zrn[2 * s + 1];
        }
        if (i < 24) {                            // prefetch index for iter i+2
            int k2 = (i + 2) * 4 + g;
            idx_n2 = (k2 <= K) ? ni[k2 - 1] : 0;
        }

        float dot = dp4(ca, za) + dp4(cb, zb);
        float tn  = dp4(za, za) + dp4(zb, zb);
        float df  = ad4(ca, za) + ad4(cb, zb);
#pragma unroll
        for (int o = 1; o < 16; o <<= 1) {
            dot += __shfl_xor(dot, o);
            tn  += __shfl_xor(tn,  o);
            df  += __shfl_xor(df,  o);
        }

        int kk = i * 4 + g;
        if (s == 0 && kk <= K) {
            float logit = dot / (cdenom * fmaxf(sqrtf(tn), EPS));
            if (kk > 0 && df == 0.0f) logit = -INFINITY;
            out[(size_t)nt * (K + 1) + kk] = logit;
        }

        za = zan; zb = zbn; idx_n = idx_n2;
    }
}

extern "C" void kernel_launch(void* const* d_in, const int* in_sizes, int n_in,
                              void* d_out, int out_size, void* d_ws, size_t ws_size,
                              hipStream_t stream) {
    const float* z   = (const float*)d_in[0];   // (N, C, L)
    const float* c   = (const float*)d_in[1];   // (N, C, L+1)
    const int*   neg = (const int*)d_in[2];     // (N, L, K)
    float* out = (float*)d_out;                 // (N*L, K+1)

    float* z_t = (float*)d_ws;                  // (N, L, C)  4 MB
    float* c_t = z_t + (size_t)N * L * C;       // (N, L, C)  4 MB

    transpose_both<<<dim3(L / 64, C / 64, 16), dim3(64, 8), 0, stream>>>(z, c, z_t, c_t);
    ssl_main<<<dim3((N * L) / 4), 256, 0, stream>>>(z_t, c_t, neg, out);
}